// Round 6
// baseline (393.689 us; speedup 1.0000x reference)
//
#include <hip/hip_runtime.h>
#include <hip/hip_fp16.h>
#include <math.h>

#define N_NODES 100000
#define N_EDGES 1600000
#define NFEAT 128
#define NHID 128
#define NS 64
#define NCLASS 16
#define BB 8192

// binned CSR build geometry
#define SUB_SHIFT 5               // 32 rows per sub-bucket
#define NSUB 3125                 // 100000 / 32
#define HWG 256                   // histogram workgroups
#define BINC_CAP 2048             // LDS edge capacity in binC

// feature slicing for XCD-resident gathers
#define NSLICE 8                  // 8 slices x 16 feats; slice = blockIdx % 8 -> XCD
#define SLICEF 16                 // feats per slice (32B f16 per node)

typedef unsigned long long ull;
typedef unsigned int uint;

// ---------------- bf16 helpers (gemm staging only) ----------------

__device__ __forceinline__ unsigned short f2bf(float f) {
  unsigned int u = __float_as_uint(f);
  return (unsigned short)((u + 0x7fffu + ((u >> 16) & 1u)) >> 16);  // RNE
}
__device__ __forceinline__ unsigned int packbf2(float lo, float hi) {
  return (unsigned int)f2bf(lo) | ((unsigned int)f2bf(hi) << 16);
}

// ---------------- f16 packed helpers ----------------

__device__ __forceinline__ __half2 h2zero() {
  return __builtin_bit_cast(__half2, 0u);
}
__device__ __forceinline__ __half2 h2shfl_add(__half2 a, int m) {
  int t = __shfl_xor(__builtin_bit_cast(int, a), m);
  return __hadd2(a, __builtin_bit_cast(__half2, t));
}
// packed relu on 2xf16 bit pattern: zero any half with sign bit set
__device__ __forceinline__ uint relu2(uint u) {
  uint mm = ((u >> 15) & 0x10001u) * 0xFFFFu;
  return u & ~mm;
}
union U4H { uint4 u4; __half2 h[4]; };

__device__ __forceinline__ void fma_row_h(__half2* acc, __half2 v, uint4 u) {
  U4H q; q.u4 = u;
#pragma unroll
  for (int k = 0; k < 4; ++k) acc[k] = __hfma2(v, q.h[k], acc[k]);
}
// edge word -> broadcast half2 of val: bits [31:17] are sign-less f16 bits
__device__ __forceinline__ __half2 edge_vh2(uint e) {
  uint hb = e >> 17;
  return __builtin_bit_cast(__half2, hb * 0x10001u);   // v_lshl_or pattern
}

// ---------------- edge packing ----------------
// 8B (bin passes): [63:34]=val[31:2], [33:17]=row, [16:0]=col
// 4B (spmm): [31:17]=f16 bits of val (sign-less, val in [0,1)), [16:0]=col

__device__ __forceinline__ ull pack_edge(float v, int r, int c) {
  return ((ull)(__float_as_uint(v) >> 2) << 34) | ((ull)(unsigned)r << 17) | (unsigned)c;
}
__device__ __forceinline__ int edge_col(ull p) { return (int)(p & 0x1FFFFu); }
__device__ __forceinline__ int edge_row(ull p) { return (int)((unsigned)(p >> 17) & 0x1FFFFu); }
__device__ __forceinline__ float edge_val(ull p) {
  return __uint_as_float(((unsigned)(p >> 34)) << 2);
}
__device__ __forceinline__ uint pack4(ull p) {
  // val in [0,1) -> positive f16, bits <= 0x3BFF < 0x8000 (15 bits)
  uint hb = (uint)__half_as_ushort(__float2half(edge_val(p)));
  return (uint)edge_col(p) | (hb << 17);
}
__device__ __forceinline__ int keep_test(const uint* keep, int r) {
  return (keep[r >> 5] >> (r & 31)) & 1u;
}

// ---------------- selection masks: sel[] + keep bitmask (flag|sel) ----------------

__global__ __launch_bounds__(256) void selbuild_kernel(const int* __restrict__ index,
                                                       int* __restrict__ sel,
                                                       uint* __restrict__ keep) {
  int t = blockIdx.x * 256 + threadIdx.x;  // 8192 exactly
  int r = index[t];
  sel[r] = 1;
  atomicOr(&keep[r >> 5], 1u << (r & 31));
}

__global__ __launch_bounds__(256) void selflag_kernel(const int* __restrict__ row,
                                                      const int* __restrict__ col,
                                                      const int* __restrict__ sel,
                                                      uint* __restrict__ keep) {
  int i = blockIdx.x * blockDim.x + threadIdx.x;
  int stride = gridDim.x * blockDim.x;
  for (; i < N_EDGES; i += stride)
    if (sel[row[i]]) {
      int c = col[i];
      atomicOr(&keep[c >> 5], 1u << (c & 31));
    }
}

// ---- packed row descriptors: one 8B load replaces rowlist->offs chain ----
// rdesc = row(17b) | start(22b)<<17 | count(14b)<<39   (runs AFTER binC; needs offs)

__global__ __launch_bounds__(256) void rdesc_kernel(const uint* __restrict__ keep,
                                                    const int* __restrict__ offs,
                                                    ull* __restrict__ rdesc,
                                                    int* __restrict__ nkept) {
  int w = blockIdx.x * 256 + threadIdx.x;
  if (w >= NSUB) return;            // 3125 words exactly cover 100000 rows
  uint b = keep[w];
  int c = __popc(b);
  if (!c) return;
  int base = atomicAdd(nkept, c);
  int r0 = w << 5;
  while (b) {
    int i = __ffs(b) - 1;
    int r = r0 + i;
    int s0 = offs[r], s1 = offs[r + 1];
    rdesc[base++] = (ull)(uint)r | ((ull)(uint)s0 << 17) | ((ull)(uint)(s1 - s0) << 39);
    b &= b - 1;
  }
}

// sdesc = start(22b) | count<<22, per selected batch element
__global__ __launch_bounds__(256) void sdesc_kernel(const int* __restrict__ index,
                                                    const int* __restrict__ offs,
                                                    ull* __restrict__ sdesc) {
  int b = blockIdx.x * 256 + threadIdx.x;  // 8192 exactly
  int r = index[b];
  int s0 = offs[r];
  sdesc[b] = (ull)(uint)s0 | ((ull)(uint)(offs[r + 1] - s0) << 22);
}

// ---------------- sub-bucket histogram (3125 bins, LDS-privatized, keep-gated) ------

__global__ __launch_bounds__(256) void histsub_kernel(const int* __restrict__ row,
                                                      const uint* __restrict__ keep,
                                                      int* __restrict__ subcnt) {
  __shared__ int lh[NSUB];
  int tid = threadIdx.x;
  for (int i = tid; i < NSUB; i += 256) lh[i] = 0;
  __syncthreads();
  for (long i = (long)blockIdx.x * 256 + tid; i < N_EDGES; i += (long)HWG * 256) {
    int r = row[i];
    if (keep_test(keep, r)) atomicAdd(&lh[r >> SUB_SHIFT], 1);
  }
  __syncthreads();
  for (int i = tid; i < NSUB; i += 256) {
    int c = lh[i];
    if (c) atomicAdd(&subcnt[i], c);
  }
}

// ---------------- scan of 3125 sub-bucket counts -> sub_offs, gcur2 (1 WG) ----

__global__ __launch_bounds__(1024) void scanall_kernel(const int* __restrict__ subcnt,
                                                       int* __restrict__ sub_offs,
                                                       int* __restrict__ gcur2) {
  __shared__ int sd[1024];
  int tid = threadIdx.x;
  int b0 = tid * 4;
  int vv[4];
  int loc = 0;
#pragma unroll
  for (int k = 0; k < 4; ++k) {
    int i = b0 + k;
    vv[k] = (i < NSUB) ? subcnt[i] : 0;
    loc += vv[k];
  }
  sd[tid] = loc;
  __syncthreads();
  for (int o = 1; o < 1024; o <<= 1) {
    int add = (tid >= o) ? sd[tid - o] : 0;
    __syncthreads();
    sd[tid] += add;
    __syncthreads();
  }
  int pre = sd[tid] - loc;
#pragma unroll
  for (int k = 0; k < 4; ++k) {
    int i = b0 + k;
    if (i < NSUB) {
      sub_offs[i] = pre;
      gcur2[i] = pre;
      pre += vv[k];
    }
  }
  if (tid == 1023) sub_offs[NSUB] = sd[1023];
}

// ---- fused bin pass: kept edges scattered directly to 3125 sub-bucket regions ----
// Replaces the former two LDS-staged passes (49-bucket binA + 64-way binB): one read
// of row/col/val, one global atomic on gcur2 (196 cache lines, high pipelining at L3),
// one 8B scattered write into the L2/L3-resident 9.4 MB edat8 region.

__global__ __launch_bounds__(256) void binAB_kernel(const int* __restrict__ row,
                                                    const int* __restrict__ col,
                                                    const float* __restrict__ val,
                                                    const uint* __restrict__ keep,
                                                    int* __restrict__ gcur2,
                                                    ull* __restrict__ edat8) {
  long i = (long)blockIdx.x * 256 + threadIdx.x;
  long stride = (long)gridDim.x * 256;
  for (; i < N_EDGES; i += stride) {
    int r = row[i];
    if (keep_test(keep, r)) {
      int pos = atomicAdd(&gcur2[r >> SUB_SHIFT], 1);
      edat8[pos] = pack_edge(val[i], r, col[i]);
    }
  }
}

// ---- pass C: exact row placement within each 32-row sub-bucket (LDS-staged) ----
// Emits offs[] and the FINAL 4B packed edges (col + sign-less f16 val).

__global__ __launch_bounds__(256) void binC_kernel(const int* __restrict__ sub_offs,
                                                   const ull* __restrict__ edat8,
                                                   ull* __restrict__ ebuf1,
                                                   uint* __restrict__ edat4,
                                                   int* __restrict__ offs) {
  __shared__ ull es[BINC_CAP];           // 16 KB
  __shared__ int rcnt[32], rcur[32];
  int s = blockIdx.x, tid = threadIdx.x;
  int r0 = s << SUB_SHIFT;
  int beg = sub_offs[s], end = sub_offs[s + 1];
  int n = end - beg;
  if (tid < 32) rcnt[tid] = 0;
  __syncthreads();
  if (n <= BINC_CAP) {
    for (int i = tid; i < n; i += 256) {
      ull p = edat8[beg + i];
      es[i] = p;
      atomicAdd(&rcnt[edge_row(p) & 31], 1);
    }
    __syncthreads();
    if (tid < 32) {
      int h = rcnt[tid];
      int x = h;
      for (int o = 1; o < 32; o <<= 1) {
        int y = __shfl_up(x, o, 32);
        if (tid >= o) x += y;
      }
      rcur[tid] = x - h;
      offs[r0 + tid] = beg + x - h;
      if (s == NSUB - 1 && tid == 31) offs[N_NODES] = end;
    }
    __syncthreads();
    for (int i = tid; i < n; i += 256) {
      ull p = es[i];
      int pos = atomicAdd(&rcur[edge_row(p) & 31], 1);
      edat4[beg + pos] = pack4(p);
    }
  } else {  // fallback: global scratch (statistically never at mean ~390)
    for (int i = tid; i < n; i += 256) {
      ull p = edat8[beg + i];
      ebuf1[beg + i] = p;
      atomicAdd(&rcnt[edge_row(p) & 31], 1);
    }
    __syncthreads();
    if (tid < 32) {
      int h = rcnt[tid];
      int x = h;
      for (int o = 1; o < 32; o <<= 1) {
        int y = __shfl_up(x, o, 32);
        if (tid >= o) x += y;
      }
      rcur[tid] = x - h;
      offs[r0 + tid] = beg + x - h;
      if (s == NSUB - 1 && tid == 31) offs[N_NODES] = end;
    }
    __syncthreads();
    for (int i = tid; i < n; i += 256) {
      ull p = ebuf1[beg + i];
      int pos = atomicAdd(&rcur[edge_row(p) & 31], 1);
      edat4[beg + pos] = pack4(p);
    }
  }
}

// ---------------- MFMA GEMM1: a = f16(x @ W1), sliced output layout --------
// 128 rows per block (two 64-row tiles) so W is staged once per 128 rows.

typedef __attribute__((ext_vector_type(8))) __bf16 bf16x8;
typedef __attribute__((ext_vector_type(4))) float f32x4;
union FragU { uint4 u; bf16x8 b; };

#define LDSTR 68   // uints per 128-feat row in LDS

__global__ __launch_bounds__(256) void gemm1_kernel(const float* __restrict__ A,
                                                    const float* __restrict__ W,
                                                    unsigned short* __restrict__ C,
                                                    int nrows) {
  __shared__ uint As_s[64 * LDSTR];    // 17.4 KB
  __shared__ uint Wt_s[128 * LDSTR];   // 34.8 KB
  int tid = threadIdx.x;

  // stage W fp32 [k][n] -> bf16 [n][k] (reads coalesced along n), once per block
  {
    int n = tid & 127, hh = tid >> 7;
#pragma unroll
    for (int kk = 0; kk < 32; ++kk) {
      int kc = hh * 32 + kk;
      Wt_s[n * LDSTR + kc] = packbf2(W[(2 * kc) * 128 + n], W[(2 * kc + 1) * 128 + n]);
    }
  }

  int w = tid >> 6, lane = tid & 63;
  int quad = lane >> 4, lr = lane & 15;
  int n0 = w * 32;

#pragma unroll
  for (int t = 0; t < 2; ++t) {
    int rbase = blockIdx.x * 128 + t * 64;
    __syncthreads();   // W ready (t=0) / previous tile's As reads complete (t=1)
    {
      const float4* src = (const float4*)(A + (long)rbase * 128);
#pragma unroll
      for (int i = 0; i < 8; ++i) {
        int f = i * 256 + tid;
        int m = f >> 5;
        float4 v = (rbase + m < nrows) ? src[f] : make_float4(0.f, 0.f, 0.f, 0.f);
        int c = (f & 31) * 2;
        As_s[m * LDSTR + c]     = packbf2(v.x, v.y);
        As_s[m * LDSTR + c + 1] = packbf2(v.z, v.w);
      }
    }
    __syncthreads();

    f32x4 acc[4][2];
#pragma unroll
    for (int mt = 0; mt < 4; ++mt)
#pragma unroll
      for (int nt = 0; nt < 2; ++nt) acc[mt][nt] = (f32x4){0.f, 0.f, 0.f, 0.f};

#pragma unroll
    for (int kk = 0; kk < 4; ++kk) {
      int kc = kk * 16 + quad * 4;
      FragU fb0, fb1;
      fb0.u = *(const uint4*)&Wt_s[(n0 + lr) * LDSTR + kc];
      fb1.u = *(const uint4*)&Wt_s[(n0 + 16 + lr) * LDSTR + kc];
#pragma unroll
      for (int mt = 0; mt < 4; ++mt) {
        FragU fa;
        fa.u = *(const uint4*)&As_s[(mt * 16 + lr) * LDSTR + kc];
        acc[mt][0] = __builtin_amdgcn_mfma_f32_16x16x32_bf16(fa.b, fb0.b, acc[mt][0], 0, 0, 0);
        acc[mt][1] = __builtin_amdgcn_mfma_f32_16x16x32_bf16(fa.b, fb1.b, acc[mt][1], 0, 0, 0);
      }
    }

#pragma unroll
    for (int mt = 0; mt < 4; ++mt) {
#pragma unroll
      for (int nt = 0; nt < 2; ++nt) {
        // col = n0 + nt*16 + lr  ->  slice = 2w+nt, within-slice feat = lr
        __half* cs = (__half*)(C + (size_t)(w * 2 + nt) * (N_NODES * SLICEF));
#pragma unroll
        for (int r = 0; r < 4; ++r) {
          int row = rbase + mt * 16 + quad * 4 + r;
          if (row < nrows) cs[(size_t)row * SLICEF + lr] = __float2half(acc[mt][nt][r]);
        }
      }
    }
  }
}

// ---- fused GEMM2 + final: t = g2@W2+b2 (MFMA) -> LDS; z = [t,s]@Wl+bl; log_softmax ----

__global__ __launch_bounds__(256) void gemm2f_kernel(const float* __restrict__ g2,
                                                     const float* __restrict__ W2,
                                                     const float* __restrict__ b2,
                                                     const float* __restrict__ s_in,
                                                     const float* __restrict__ Wl,
                                                     const float* __restrict__ bl,
                                                     float* __restrict__ out) {
  __shared__ uint smem[13056];               // 52.2 KB
  uint* Wt_s = smem;                         // [128*68]
  uint* As_s = smem + 128 * LDSTR;           // [64*68]
  float* ts  = (float*)smem;                 // 64 x 129 fp32 (8256 <= 8704, inside Wt area)
  float* Wls = (float*)(smem + 128 * LDSTR); // 3072 fp32 (reuses As area)
  int tid = threadIdx.x;
  int rbase = blockIdx.x * 64;               // grid = 128, exact

  {
    int n = tid & 127, hh = tid >> 7;
#pragma unroll
    for (int kk = 0; kk < 32; ++kk) {
      int kc = hh * 32 + kk;
      Wt_s[n * LDSTR + kc] = packbf2(W2[(2 * kc) * 128 + n], W2[(2 * kc + 1) * 128 + n]);
    }
  }
  {
    const float4* src = (const float4*)(g2 + (long)rbase * 128);
#pragma unroll
    for (int i = 0; i < 8; ++i) {
      int f = i * 256 + tid;
      int m = f >> 5, c = (f & 31) * 2;
      float4 v = src[f];
      As_s[m * LDSTR + c]     = packbf2(v.x, v.y);
      As_s[m * LDSTR + c + 1] = packbf2(v.z, v.w);
    }
  }
  __syncthreads();

  int w = tid >> 6, lane = tid & 63;
  int quad = lane >> 4, lr = lane & 15;
  int n0 = w * 32;

  f32x4 acc[4][2];
#pragma unroll
  for (int mt = 0; mt < 4; ++mt)
#pragma unroll
    for (int nt = 0; nt < 2; ++nt) acc[mt][nt] = (f32x4){0.f, 0.f, 0.f, 0.f};

#pragma unroll
  for (int kk = 0; kk < 4; ++kk) {
    int kc = kk * 16 + quad * 4;
    FragU fb0, fb1;
    fb0.u = *(const uint4*)&Wt_s[(n0 + lr) * LDSTR + kc];
    fb1.u = *(const uint4*)&Wt_s[(n0 + 16 + lr) * LDSTR + kc];
#pragma unroll
    for (int mt = 0; mt < 4; ++mt) {
      FragU fa;
      fa.u = *(const uint4*)&As_s[(mt * 16 + lr) * LDSTR + kc];
      acc[mt][0] = __builtin_amdgcn_mfma_f32_16x16x32_bf16(fa.b, fb0.b, acc[mt][0], 0, 0, 0);
      acc[mt][1] = __builtin_amdgcn_mfma_f32_16x16x32_bf16(fa.b, fb1.b, acc[mt][1], 0, 0, 0);
    }
  }
  __syncthreads();   // all LDS reads complete before region reuse

  // t -> LDS (stride 129: conflict-free column reads); stage Wl
#pragma unroll
  for (int mt = 0; mt < 4; ++mt) {
#pragma unroll
    for (int nt = 0; nt < 2; ++nt) {
      int col = n0 + nt * 16 + lr;
      float bv = b2[col];
#pragma unroll
      for (int r = 0; r < 4; ++r)
        ts[(mt * 16 + quad * 4 + r) * 129 + col] = acc[mt][nt][r] + bv;
    }
  }
  for (int i = tid; i < 192 * 16; i += 256) Wls[i] = Wl[i];
  __syncthreads();

  // z = [t, s] @ Wl + bl; 4 lanes per row, 48 k-dims each, shfl reduce
  int q = lane & 3;
  int mrow = w * 16 + (lane >> 2);
  int b = rbase + mrow;
  float z[16];
#pragma unroll
  for (int c = 0; c < 16; ++c) z[c] = 0.f;
  int k0 = q * 48;
  for (int kk = 0; kk < 48; ++kk) {
    int k = k0 + kk;
    float xv = (k < 128) ? ts[mrow * 129 + k] : s_in[(long)b * 64 + (k - 128)];
    const float* wp = Wls + k * 16;
#pragma unroll
    for (int c = 0; c < 16; ++c) z[c] = fmaf(xv, wp[c], z[c]);
  }
#pragma unroll
  for (int c = 0; c < 16; ++c) {
    z[c] += __shfl_xor(z[c], 1);
    z[c] += __shfl_xor(z[c], 2);
  }
  if (q == 0) {
#pragma unroll
    for (int c = 0; c < 16; ++c) z[c] += bl[c];
    float mx = z[0];
#pragma unroll
    for (int c = 1; c < 16; ++c) mx = fmaxf(mx, z[c]);
    float sum = 0.f;
#pragma unroll
    for (int c = 0; c < 16; ++c) sum += expf(z[c] - mx);
    float lse = mx + logf(sum);
    float4* ob = (float4*)(out + (long)b * 16);
    ob[0] = make_float4(z[0] - lse, z[1] - lse, z[2] - lse, z[3] - lse);
    ob[1] = make_float4(z[4] - lse, z[5] - lse, z[6] - lse, z[7] - lse);
    ob[2] = make_float4(z[8] - lse, z[9] - lse, z[10] - lse, z[11] - lse);
    ob[3] = make_float4(z[12] - lse, z[13] - lse, z[14] - lse, z[15] - lse);
  }
}

// ---- sliced CSR spmm, f16 packed math, descriptor-fed, unroll-4 gathers ----
// (unchanged from R5: 57.6 us, FETCH ~43 MB -- control for this round)

__global__ __launch_bounds__(256) void spmm_row_kernel(const ull* __restrict__ rdesc,
                                                       const uint* __restrict__ edat4,
                                                       const unsigned short* __restrict__ a,
                                                       const float* __restrict__ bias,
                                                       unsigned short* __restrict__ h1,
                                                       const int* __restrict__ nkept) {
  int nk = *nkept;
  int rblk = blockIdx.x >> 3;
  if (rblk * 32 >= nk) return;                 // wave-uniform early exit
  int s = blockIdx.x & 7;                      // slice -> XCD
  int tid = threadIdx.x, lane = tid & 63;
  int li = rblk * 32 + (tid >> 3);             // 32 rows per block (8/wave)
  int g = (lane >> 1) & 3, h = lane & 1, h8 = h * 8;
  const unsigned short* as = a + (size_t)s * (N_NODES * SLICEF);
  bool active = li < nk;
  int r = 0, j = 0, jend = 0;
  if (active) {
    ull d = rdesc[li];
    r = (int)(d & 0x1FFFFu);
    int start = (int)((d >> 17) & 0x3FFFFFu);
    j = start + g;
    jend = start + (int)(d >> 39);
  }
  __half2 acc[4] = {h2zero(), h2zero(), h2zero(), h2zero()};
  for (; j + 12 < jend; j += 16) {
    uint e0 = edat4[j];
    uint e1 = edat4[j + 4];
    uint e2 = edat4[j + 8];
    uint e3 = edat4[j + 12];
    uint4 u0 = *(const uint4*)(as + (size_t)(e0 & 0x1FFFFu) * SLICEF + h8);
    uint4 u1 = *(const uint4*)(as + (size_t)(e1 & 0x1FFFFu) * SLICEF + h8);
    uint4 u2 = *(const uint4*)(as + (size_t)(e2 & 0x1FFFFu) * SLICEF + h8);
    uint4 u3 = *(const uint4*)(as + (size_t)(e3 & 0x1FFFFu) * SLICEF + h8);
    fma_row_h(acc, edge_vh2(e0), u0);
    fma_row_h(acc, edge_vh2(e1), u1);
    fma_row_h(acc, edge_vh2(e2), u2);
    fma_row_h(acc, edge_vh2(e3), u3);
  }
  if (j + 4 < jend) {                          // 2-edge tail
    uint e0 = edat4[j];
    uint e1 = edat4[j + 4];
    uint4 u0 = *(const uint4*)(as + (size_t)(e0 & 0x1FFFFu) * SLICEF + h8);
    uint4 u1 = *(const uint4*)(as + (size_t)(e1 & 0x1FFFFu) * SLICEF + h8);
    fma_row_h(acc, edge_vh2(e0), u0);
    fma_row_h(acc, edge_vh2(e1), u1);
    j += 8;
  }
  if (j < jend) {                              // 1-edge tail
    uint e = edat4[j];
    uint4 u = *(const uint4*)(as + (size_t)(e & 0x1FFFFu) * SLICEF + h8);
    fma_row_h(acc, edge_vh2(e), u);
  }
#pragma unroll
  for (int k = 0; k < 4; ++k) {
    acc[k] = h2shfl_add(acc[k], 2);
    acc[k] = h2shfl_add(acc[k], 4);
  }
  if (active && (lane & 6) == 0) {             // g == 0 lanes: h=0,1 hold final 16 feats
    const float* bp = bias + s * SLICEF + h8;
    float4 b0 = *(const float4*)bp;
    float4 b1v = *(const float4*)(bp + 4);
    uint4 o;
    o.x = relu2(__builtin_bit_cast(uint, __hadd2(acc[0], __floats2half2_rn(b0.x, b0.y))));
    o.y = relu2(__builtin_bit_cast(uint, __hadd2(acc[1], __floats2half2_rn(b0.z, b0.w))));
    o.z = relu2(__builtin_bit_cast(uint, __hadd2(acc[2], __floats2half2_rn(b1v.x, b1v.y))));
    o.w = relu2(__builtin_bit_cast(uint, __hadd2(acc[3], __floats2half2_rn(b1v.z, b1v.w))));
    *(uint4*)(h1 + (size_t)s * (N_NODES * SLICEF) + (size_t)r * SLICEF + h8) = o;
  }
}

__global__ __launch_bounds__(256) void spmm_sel_kernel(const ull* __restrict__ sdesc,
                                                       const uint* __restrict__ edat4,
                                                       const unsigned short* __restrict__ h1,
                                                       float* __restrict__ g2) {
  int s = blockIdx.x & 7;
  int bblk = blockIdx.x >> 3;
  int tid = threadIdx.x, lane = tid & 63;
  int b = bblk * 32 + (tid >> 3);              // grid = (8192/32)*8, exact
  int g = (lane >> 1) & 3, h = lane & 1, h8 = h * 8;
  const unsigned short* hs = h1 + (size_t)s * (N_NODES * SLICEF);
  ull d = sdesc[b];
  int start = (int)(d & 0x3FFFFFu);
  int j = start + g, jend = start + (int)(d >> 22);
  __half2 acc[4] = {h2zero(), h2zero(), h2zero(), h2zero()};
  for (; j + 12 < jend; j += 16) {
    uint e0 = edat4[j];
    uint e1 = edat4[j + 4];
    uint e2 = edat4[j + 8];
    uint e3 = edat4[j + 12];
    uint4 u0 = *(const uint4*)(hs + (size_t)(e0 & 0x1FFFFu) * SLICEF + h8);
    uint4 u1 = *(const uint4*)(hs + (size_t)(e1 & 0x1FFFFu) * SLICEF + h8);
    uint4 u2 = *(const uint4*)(hs + (size_t)(e2 & 0x1FFFFu) * SLICEF + h8);
    uint4 u3 = *(const uint4*)(hs + (size_t)(e3 & 0x1FFFFu) * SLICEF + h8);
    fma_row_h(acc, edge_vh2(e0), u0);
    fma_row_h(acc, edge_vh2(e1), u1);
    fma_row_h(acc, edge_vh2(e2), u2);
    fma_row_h(acc, edge_vh2(e3), u3);
  }
  if (j + 4 < jend) {
    uint e0 = edat4[j];
    uint e1 = edat4[j + 4];
    uint4 u0 = *(const uint4*)(hs + (size_t)(e0 & 0x1FFFFu) * SLICEF + h8);
    uint4 u1 = *(const uint4*)(hs + (size_t)(e1 & 0x1FFFFu) * SLICEF + h8);
    fma_row_h(acc, edge_vh2(e0), u0);
    fma_row_h(acc, edge_vh2(e1), u1);
    j += 8;
  }
  if (j < jend) {
    uint e = edat4[j];
    uint4 u = *(const uint4*)(hs + (size_t)(e & 0x1FFFFu) * SLICEF + h8);
    fma_row_h(acc, edge_vh2(e), u);
  }
#pragma unroll
  for (int k = 0; k < 4; ++k) {
    acc[k] = h2shfl_add(acc[k], 2);
    acc[k] = h2shfl_add(acc[k], 4);
  }
  if ((lane & 6) == 0) {
    float* op = g2 + (size_t)b * 128 + s * SLICEF + h8;
    *(float4*)op = make_float4(__low2float(acc[0]), __high2float(acc[0]),
                               __low2float(acc[1]), __high2float(acc[1]));
    *(float4*)(op + 4) = make_float4(__low2float(acc[2]), __high2float(acc[2]),
                                     __low2float(acc[3]), __high2float(acc[3]));
  }
}

// ---------------- launch ----------------

extern "C" void kernel_launch(void* const* d_in, const int* in_sizes, int n_in,
                              void* d_out, int out_size, void* d_ws, size_t ws_size,
                              hipStream_t stream) {
  const float* s_in  = (const float*)d_in[0];
  const float* x     = (const float*)d_in[1];
  const int*   row   = (const int*)d_in[2];
  const int*   col   = (const int*)d_in[3];
  const float* val   = (const float*)d_in[4];
  const int*   index = (const int*)d_in[5];
  const float* W1    = (const float*)d_in[6];
  const float* b1    = (const float*)d_in[7];
  const float* W2    = (const float*)d_in[8];
  const float* b2    = (const float*)d_in[9];
  const float* Wl    = (const float*)d_in[10];
  const float* bl    = (const float*)d_in[11];
  float* out = (float*)d_out;

  // workspace carve (~82 MB), 8B-aligned first
  ull* edat8 = (ull*)d_ws;                                           // [1.6M] binAB out (8B edges)
  ull* ebuf1 = edat8 + N_EDGES;                                      // [1.6M] binC fallback scratch
  uint* edat4 = (uint*)ebuf1;                                        // ALIAS: final 4B edges (binC out).
  // Safe: binC fallback scratch at byte 8*beg never overlaps edat4 writes
  // (<= byte 4*(beg+n) <= 8*beg whenever n <= beg; fallback needs n > 2048,
  // p < 1e-100 at mean ~390 edges/sub-bucket).
  ull* rdesc = edat8;                                                // ALIAS: edat8 dead after binC
  ull* sdesc = edat8 + N_NODES;                                      // [8192] after rdesc[100000]
  unsigned short* a  = (unsigned short*)(ebuf1 + N_EDGES);           // sliced xW1 f16 [8][100000][16]
  unsigned short* h1 = a + (size_t)N_NODES * 128;                    // sliced layer1 f16 [8][100000][16]
  float* g2   = (float*)(h1 + (size_t)N_NODES * 128);                // sel spmm   [8192,128]
  int* sel    = (int*)(g2 + (size_t)BB * 128);                       // [100000] selected mask
  int* subcnt = sel + N_NODES;                                       // [3125]
  uint* keep  = (uint*)(subcnt + NSUB);                              // [3125] flag|sel bitmask
  int* offs   = (int*)(keep + NSUB);                                 // [100001] (binC writes)
  int* sub_offs = offs + (N_NODES + 1);                              // [3126]
  int* gcur2  = sub_offs + (NSUB + 1);                               // [3125]
  int* nkept  = gcur2 + NSUB;                                        // [1]

  hipMemsetAsync(sel, 0, (N_NODES + 2 * NSUB) * sizeof(int), stream);  // sel+subcnt+keep
  hipMemsetAsync(nkept, 0, sizeof(int), stream);

  selbuild_kernel<<<BB / 256, 256, 0, stream>>>(index, sel, keep);
  selflag_kernel<<<4096, 256, 0, stream>>>(row, col, sel, keep);
  histsub_kernel<<<HWG, 256, 0, stream>>>(row, keep, subcnt);
  scanall_kernel<<<1, 1024, 0, stream>>>(subcnt, sub_offs, gcur2);

  binAB_kernel<<<2048, 256, 0, stream>>>(row, col, val, keep, gcur2, edat8);
  binC_kernel<<<NSUB, 256, 0, stream>>>(sub_offs, edat8, ebuf1, edat4, offs);

  // descriptors (need offs; edat8 dead -> rdesc/sdesc alias it)
  rdesc_kernel<<<(NSUB + 255) / 256, 256, 0, stream>>>(keep, offs, rdesc, nkept);
  sdesc_kernel<<<BB / 256, 256, 0, stream>>>(index, offs, sdesc);

  gemm1_kernel<<<(N_NODES + 127) / 128, 256, 0, stream>>>(x, W1, a, N_NODES);
  spmm_row_kernel<<<NSUB * NSLICE, 256, 0, stream>>>(rdesc, edat4, a, b1, h1, nkept);
  spmm_sel_kernel<<<(BB / 32) * NSLICE, 256, 0, stream>>>(sdesc, edat4, h1, g2);
  gemm2f_kernel<<<BB / 64, 256, 0, stream>>>(g2, W2, b2, s_in, Wl, bl, out);
}

// Round 7
// 296.003 us; speedup vs baseline: 1.3300x; 1.3300x over previous
//
#include <hip/hip_runtime.h>
#include <hip/hip_fp16.h>
#include <math.h>

#define N_NODES 100000
#define N_EDGES 1600000
#define NFEAT 128
#define NHID 128
#define NS 64
#define NCLASS 16
#define BB 8192

// binned CSR build geometry (R0-proven)
#define B1_SHIFT 11               // 2048 rows per L1 bucket
#define NB1 49                    // ceil(100000 / 2048)
#define SUB_SHIFT 5               // 32 rows per sub-bucket
#define NSUB 3125                 // 100000 / 32
#define CHUNKA 2048               // edges per block-iteration in bin passes
#define HWG 256                   // histogram workgroups
#define BINC_CAP 2048             // LDS edge capacity in binC

typedef unsigned long long ull;
typedef unsigned int uint;

// ---------------- bf16 helpers (gemm staging only) ----------------

__device__ __forceinline__ unsigned short f2bf(float f) {
  unsigned int u = __float_as_uint(f);
  return (unsigned short)((u + 0x7fffu + ((u >> 16) & 1u)) >> 16);  // RNE
}
__device__ __forceinline__ unsigned int packbf2(float lo, float hi) {
  return (unsigned int)f2bf(lo) | ((unsigned int)f2bf(hi) << 16);
}

// ---------------- f16 packed helpers ----------------

__device__ __forceinline__ __half2 h2zero() {
  return __builtin_bit_cast(__half2, 0u);
}
__device__ __forceinline__ __half2 h2shfl_add(__half2 a, int m) {
  int t = __shfl_xor(__builtin_bit_cast(int, a), m);
  return __hadd2(a, __builtin_bit_cast(__half2, t));
}
// packed relu on 2xf16 bit pattern: zero any half with sign bit set
__device__ __forceinline__ uint relu2(uint u) {
  uint mm = ((u >> 15) & 0x10001u) * 0xFFFFu;
  return u & ~mm;
}
union U4H { uint4 u4; __half2 h[4]; };

__device__ __forceinline__ void fma_row_h(__half2* acc, __half2 v, uint4 u) {
  U4H q; q.u4 = u;
#pragma unroll
  for (int k = 0; k < 4; ++k) acc[k] = __hfma2(v, q.h[k], acc[k]);
}
// edge word -> broadcast half2 of val: bits [31:17] are sign-less f16 bits
__device__ __forceinline__ __half2 edge_vh2(uint e) {
  uint hb = e >> 17;
  return __builtin_bit_cast(__half2, hb * 0x10001u);
}

// ---------------- edge packing ----------------
// 8B (bin passes): [63:34]=val[31:2], [33:17]=row, [16:0]=col
// 4B (spmm): [31:17]=f16 bits of val (sign-less, val in [0,1)), [16:0]=col

__device__ __forceinline__ ull pack_edge(float v, int r, int c) {
  return ((ull)(__float_as_uint(v) >> 2) << 34) | ((ull)(unsigned)r << 17) | (unsigned)c;
}
__device__ __forceinline__ int edge_col(ull p) { return (int)(p & 0x1FFFFu); }
__device__ __forceinline__ int edge_row(ull p) { return (int)((unsigned)(p >> 17) & 0x1FFFFu); }
__device__ __forceinline__ float edge_val(ull p) {
  return __uint_as_float(((unsigned)(p >> 34)) << 2);
}
__device__ __forceinline__ uint pack4(ull p) {
  uint hb = (uint)__half_as_ushort(__float2half(edge_val(p)));
  return (uint)edge_col(p) | (hb << 17);
}
__device__ __forceinline__ int keep_test(const uint* keep, int r) {
  return (keep[r >> 5] >> (r & 31)) & 1u;
}

// ---------------- selection masks: sel[] + keep bitmask (flag|sel) ----------------

__global__ __launch_bounds__(256) void selbuild_kernel(const int* __restrict__ index,
                                                       int* __restrict__ sel,
                                                       uint* __restrict__ keep) {
  int t = blockIdx.x * 256 + threadIdx.x;  // 8192 exactly
  int r = index[t];
  sel[r] = 1;
  atomicOr(&keep[r >> 5], 1u << (r & 31));
}

__global__ __launch_bounds__(256) void selflag_kernel(const int* __restrict__ row,
                                                      const int* __restrict__ col,
                                                      const int* __restrict__ sel,
                                                      uint* __restrict__ keep) {
  int i = blockIdx.x * blockDim.x + threadIdx.x;
  int stride = gridDim.x * blockDim.x;
  for (; i < N_EDGES; i += stride)
    if (sel[row[i]]) {
      int c = col[i];
      atomicOr(&keep[c >> 5], 1u << (c & 31));
    }
}

// ---------------- sub-bucket histogram (3125 bins, LDS-privatized, keep-gated) ------

__global__ __launch_bounds__(256) void histsub_kernel(const int* __restrict__ row,
                                                      const uint* __restrict__ keep,
                                                      int* __restrict__ subcnt) {
  __shared__ int lh[NSUB];
  int tid = threadIdx.x;
  for (int i = tid; i < NSUB; i += 256) lh[i] = 0;
  __syncthreads();
  for (long i = (long)blockIdx.x * 256 + tid; i < N_EDGES; i += (long)HWG * 256) {
    int r = row[i];
    if (keep_test(keep, r)) atomicAdd(&lh[r >> SUB_SHIFT], 1);
  }
  __syncthreads();
  for (int i = tid; i < NSUB; i += 256) {
    int c = lh[i];
    if (c) atomicAdd(&subcnt[i], c);
  }
}

// ---------------- scan of 3125 sub-bucket counts -> sub_offs, gcur1, gcur2 (1 WG) ----

__global__ __launch_bounds__(1024) void scanall_kernel(const int* __restrict__ subcnt,
                                                       int* __restrict__ sub_offs,
                                                       int* __restrict__ gcur1,
                                                       int* __restrict__ gcur2) {
  __shared__ int sd[1024];
  int tid = threadIdx.x;
  int b0 = tid * 4;
  int vv[4];
  int loc = 0;
#pragma unroll
  for (int k = 0; k < 4; ++k) {
    int i = b0 + k;
    vv[k] = (i < NSUB) ? subcnt[i] : 0;
    loc += vv[k];
  }
  sd[tid] = loc;
  __syncthreads();
  for (int o = 1; o < 1024; o <<= 1) {
    int add = (tid >= o) ? sd[tid - o] : 0;
    __syncthreads();
    sd[tid] += add;
    __syncthreads();
  }
  int pre = sd[tid] - loc;
#pragma unroll
  for (int k = 0; k < 4; ++k) {
    int i = b0 + k;
    if (i < NSUB) {
      sub_offs[i] = pre;
      gcur2[i] = pre;
      if ((i & 63) == 0) gcur1[i >> 6] = pre;
      pre += vv[k];
    }
  }
  if (tid == 1023) sub_offs[NSUB] = sd[1023];
}

// ---- pass A: kept edges -> 49 L1 bucket regions (R0-proven geometry) ----

__global__ __launch_bounds__(256) void binA_kernel(const int* __restrict__ row,
                                                   const int* __restrict__ col,
                                                   const float* __restrict__ val,
                                                   const uint* __restrict__ keep,
                                                   int* __restrict__ gcur1,
                                                   ull* __restrict__ ebuf1) {
  __shared__ ull stage[CHUNKA];          // 16 KB
  __shared__ short bkt[CHUNKA];          // 4 KB
  __shared__ int hist[NB1], lofs[NB1 + 1], lcur[NB1], gbase[NB1];
  int tid = threadIdx.x;
  for (long base = (long)blockIdx.x * CHUNKA; base < N_EDGES; base += (long)gridDim.x * CHUNKA) {
    int cnt = (int)min((long)CHUNKA, (long)N_EDGES - base);
    if (tid < NB1) hist[tid] = 0;
    __syncthreads();
    ull e[8]; int bk[8];
#pragma unroll
    for (int v = 0; v < 8; ++v) {
      int i = v * 256 + tid;
      bk[v] = -1;
      if (i < cnt) {
        long g = base + i;
        int r = row[g];
        if (keep_test(keep, r)) {
          e[v] = pack_edge(val[g], r, col[g]);
          bk[v] = r >> B1_SHIFT;
          atomicAdd(&hist[bk[v]], 1);
        }
      }
    }
    __syncthreads();
    if (tid < 64) {
      int h = (tid < NB1) ? hist[tid] : 0;
      int x = h;
      for (int o = 1; o < 64; o <<= 1) {
        int y = __shfl_up(x, o);
        if (tid >= o) x += y;
      }
      if (tid < NB1) { lofs[tid] = x - h; lcur[tid] = x - h; }
      if (tid == 63) lofs[NB1] = x;  // kept count in chunk
    }
    __syncthreads();
#pragma unroll
    for (int v = 0; v < 8; ++v) {
      if (bk[v] >= 0) {
        int pos = atomicAdd(&lcur[bk[v]], 1);
        stage[pos] = e[v];
        bkt[pos] = (short)bk[v];
      }
    }
    __syncthreads();
    if (tid < NB1) {
      int h = hist[tid];
      if (h > 0) gbase[tid] = atomicAdd(&gcur1[tid], h);
    }
    __syncthreads();
    int tot = lofs[NB1];
    for (int s = tid; s < tot; s += 256) {
      int lo = bkt[s];
      ebuf1[gbase[lo] + (s - lofs[lo])] = stage[s];
    }
    __syncthreads();
  }
}

// ---------------- pass B: L1 bucket -> 64 sub-bucket regions (R0-proven geometry) ------

__global__ __launch_bounds__(256) void binB_kernel(const ull* __restrict__ ebuf1,
                                                   const int* __restrict__ sub_offs,
                                                   int* __restrict__ gcur2,
                                                   ull* __restrict__ edat8) {
  __shared__ ull stage[CHUNKA];          // 16 KB
  __shared__ short bkt[CHUNKA];          // 4 KB
  __shared__ int hist[64], lofs[65], lcur[64], gbase[64];
  int tid = threadIdx.x;
  int b1 = blockIdx.x >> 3, w = blockIdx.x & 7;
  int rbeg = sub_offs[b1 << 6];
  int rend = sub_offs[min((b1 + 1) << 6, NSUB)];
  for (int base = rbeg + w * CHUNKA; base < rend; base += 8 * CHUNKA) {
    int cnt = min(CHUNKA, rend - base);
    if (tid < 64) hist[tid] = 0;
    __syncthreads();
    ull e[8]; int bk[8];
#pragma unroll
    for (int v = 0; v < 8; ++v) {
      int i = v * 256 + tid;
      bk[v] = -1;
      if (i < cnt) {
        e[v] = ebuf1[base + i];
        bk[v] = (edge_row(e[v]) >> SUB_SHIFT) - (b1 << 6);
        atomicAdd(&hist[bk[v]], 1);
      }
    }
    __syncthreads();
    if (tid < 64) {
      int h = hist[tid];
      int x = h;
      for (int o = 1; o < 64; o <<= 1) {
        int y = __shfl_up(x, o);
        if (tid >= o) x += y;
      }
      lofs[tid] = x - h;
      lcur[tid] = x - h;
      if (tid == 63) lofs[64] = x;  // == cnt
    }
    __syncthreads();
#pragma unroll
    for (int v = 0; v < 8; ++v) {
      if (bk[v] >= 0) {
        int pos = atomicAdd(&lcur[bk[v]], 1);
        stage[pos] = e[v];
        bkt[pos] = (short)bk[v];
      }
    }
    __syncthreads();
    if (tid < 64) {
      int h = hist[tid];
      if (h > 0) gbase[tid] = atomicAdd(&gcur2[(b1 << 6) + tid], h);
    }
    __syncthreads();
    for (int s = tid; s < cnt; s += 256) {
      int lo = bkt[s];
      edat8[gbase[lo] + (s - lofs[lo])] = stage[s];
    }
    __syncthreads();
  }
}

// ---- pass C: exact row placement within each 32-row sub-bucket (LDS-staged) ----
// Emits offs[] and the FINAL 4B packed edges (col + sign-less f16 val).

__global__ __launch_bounds__(256) void binC_kernel(const int* __restrict__ sub_offs,
                                                   const ull* __restrict__ edat8,
                                                   ull* __restrict__ ebuf1,
                                                   uint* __restrict__ edat4,
                                                   int* __restrict__ offs) {
  __shared__ ull es[BINC_CAP];           // 16 KB
  __shared__ int rcnt[32], rcur[32];
  int s = blockIdx.x, tid = threadIdx.x;
  int r0 = s << SUB_SHIFT;
  int beg = sub_offs[s], end = sub_offs[s + 1];
  int n = end - beg;
  if (tid < 32) rcnt[tid] = 0;
  __syncthreads();
  if (n <= BINC_CAP) {
    for (int i = tid; i < n; i += 256) {
      ull p = edat8[beg + i];
      es[i] = p;
      atomicAdd(&rcnt[edge_row(p) & 31], 1);
    }
    __syncthreads();
    if (tid < 32) {
      int h = rcnt[tid];
      int x = h;
      for (int o = 1; o < 32; o <<= 1) {
        int y = __shfl_up(x, o, 32);
        if (tid >= o) x += y;
      }
      rcur[tid] = x - h;
      offs[r0 + tid] = beg + x - h;
      if (s == NSUB - 1 && tid == 31) offs[N_NODES] = end;
    }
    __syncthreads();
    for (int i = tid; i < n; i += 256) {
      ull p = es[i];
      int pos = atomicAdd(&rcur[edge_row(p) & 31], 1);
      edat4[beg + pos] = pack4(p);
    }
  } else {  // fallback: global scratch (statistically never at mean ~390)
    for (int i = tid; i < n; i += 256) {
      ull p = edat8[beg + i];
      ebuf1[beg + i] = p;
      atomicAdd(&rcnt[edge_row(p) & 31], 1);
    }
    __syncthreads();
    if (tid < 32) {
      int h = rcnt[tid];
      int x = h;
      for (int o = 1; o < 32; o <<= 1) {
        int y = __shfl_up(x, o, 32);
        if (tid >= o) x += y;
      }
      rcur[tid] = x - h;
      offs[r0 + tid] = beg + x - h;
      if (s == NSUB - 1 && tid == 31) offs[N_NODES] = end;
    }
    __syncthreads();
    for (int i = tid; i < n; i += 256) {
      ull p = ebuf1[beg + i];
      int pos = atomicAdd(&rcur[edge_row(p) & 31], 1);
      edat4[beg + pos] = pack4(p);
    }
  }
}

// ---------------- MFMA GEMM1: a = f16(x @ W1), full-row layout [N][128] --------
// 128 rows per block (two 64-row tiles) so W is staged once per 128 rows.

typedef __attribute__((ext_vector_type(8))) __bf16 bf16x8;
typedef __attribute__((ext_vector_type(4))) float f32x4;
union FragU { uint4 u; bf16x8 b; };

#define LDSTR 68   // uints per 128-feat row in LDS

__global__ __launch_bounds__(256) void gemm1_kernel(const float* __restrict__ A,
                                                    const float* __restrict__ W,
                                                    unsigned short* __restrict__ C,
                                                    int nrows) {
  __shared__ uint As_s[64 * LDSTR];    // 17.4 KB
  __shared__ uint Wt_s[128 * LDSTR];   // 34.8 KB
  int tid = threadIdx.x;

  // stage W fp32 [k][n] -> bf16 [n][k] (reads coalesced along n), once per block
  {
    int n = tid & 127, hh = tid >> 7;
#pragma unroll
    for (int kk = 0; kk < 32; ++kk) {
      int kc = hh * 32 + kk;
      Wt_s[n * LDSTR + kc] = packbf2(W[(2 * kc) * 128 + n], W[(2 * kc + 1) * 128 + n]);
    }
  }

  int w = tid >> 6, lane = tid & 63;
  int quad = lane >> 4, lr = lane & 15;
  int n0 = w * 32;

#pragma unroll
  for (int t = 0; t < 2; ++t) {
    int rbase = blockIdx.x * 128 + t * 64;
    __syncthreads();   // W ready (t=0) / previous tile's As reads complete (t=1)
    {
      const float4* src = (const float4*)(A + (long)rbase * 128);
#pragma unroll
      for (int i = 0; i < 8; ++i) {
        int f = i * 256 + tid;
        int m = f >> 5;
        float4 v = (rbase + m < nrows) ? src[f] : make_float4(0.f, 0.f, 0.f, 0.f);
        int c = (f & 31) * 2;
        As_s[m * LDSTR + c]     = packbf2(v.x, v.y);
        As_s[m * LDSTR + c + 1] = packbf2(v.z, v.w);
      }
    }
    __syncthreads();

    f32x4 acc[4][2];
#pragma unroll
    for (int mt = 0; mt < 4; ++mt)
#pragma unroll
      for (int nt = 0; nt < 2; ++nt) acc[mt][nt] = (f32x4){0.f, 0.f, 0.f, 0.f};

#pragma unroll
    for (int kk = 0; kk < 4; ++kk) {
      int kc = kk * 16 + quad * 4;
      FragU fb0, fb1;
      fb0.u = *(const uint4*)&Wt_s[(n0 + lr) * LDSTR + kc];
      fb1.u = *(const uint4*)&Wt_s[(n0 + 16 + lr) * LDSTR + kc];
#pragma unroll
      for (int mt = 0; mt < 4; ++mt) {
        FragU fa;
        fa.u = *(const uint4*)&As_s[(mt * 16 + lr) * LDSTR + kc];
        acc[mt][0] = __builtin_amdgcn_mfma_f32_16x16x32_bf16(fa.b, fb0.b, acc[mt][0], 0, 0, 0);
        acc[mt][1] = __builtin_amdgcn_mfma_f32_16x16x32_bf16(fa.b, fb1.b, acc[mt][1], 0, 0, 0);
      }
    }

    __half* cs = (__half*)C;
#pragma unroll
    for (int mt = 0; mt < 4; ++mt) {
#pragma unroll
      for (int nt = 0; nt < 2; ++nt) {
        int col = n0 + nt * 16 + lr;
#pragma unroll
        for (int r = 0; r < 4; ++r) {
          int row = rbase + mt * 16 + quad * 4 + r;
          if (row < nrows) cs[(size_t)row * 128 + col] = __float2half(acc[mt][nt][r]);
        }
      }
    }
  }
}

// ---- fused GEMM2 + final: t = g2@W2+b2 (MFMA) -> LDS; z = [t,s]@Wl+bl; log_softmax ----

__global__ __launch_bounds__(256) void gemm2f_kernel(const float* __restrict__ g2,
                                                     const float* __restrict__ W2,
                                                     const float* __restrict__ b2,
                                                     const float* __restrict__ s_in,
                                                     const float* __restrict__ Wl,
                                                     const float* __restrict__ bl,
                                                     float* __restrict__ out) {
  __shared__ uint smem[13056];               // 52.2 KB
  uint* Wt_s = smem;                         // [128*68]
  uint* As_s = smem + 128 * LDSTR;           // [64*68]
  float* ts  = (float*)smem;                 // 64 x 129 fp32 (8256 <= 8704, inside Wt area)
  float* Wls = (float*)(smem + 128 * LDSTR); // 3072 fp32 (reuses As area)
  int tid = threadIdx.x;
  int rbase = blockIdx.x * 64;               // grid = 128, exact

  {
    int n = tid & 127, hh = tid >> 7;
#pragma unroll
    for (int kk = 0; kk < 32; ++kk) {
      int kc = hh * 32 + kk;
      Wt_s[n * LDSTR + kc] = packbf2(W2[(2 * kc) * 128 + n], W2[(2 * kc + 1) * 128 + n]);
    }
  }
  {
    const float4* src = (const float4*)(g2 + (long)rbase * 128);
#pragma unroll
    for (int i = 0; i < 8; ++i) {
      int f = i * 256 + tid;
      int m = f >> 5, c = (f & 31) * 2;
      float4 v = src[f];
      As_s[m * LDSTR + c]     = packbf2(v.x, v.y);
      As_s[m * LDSTR + c + 1] = packbf2(v.z, v.w);
    }
  }
  __syncthreads();

  int w = tid >> 6, lane = tid & 63;
  int quad = lane >> 4, lr = lane & 15;
  int n0 = w * 32;

  f32x4 acc[4][2];
#pragma unroll
  for (int mt = 0; mt < 4; ++mt)
#pragma unroll
    for (int nt = 0; nt < 2; ++nt) acc[mt][nt] = (f32x4){0.f, 0.f, 0.f, 0.f};

#pragma unroll
  for (int kk = 0; kk < 4; ++kk) {
    int kc = kk * 16 + quad * 4;
    FragU fb0, fb1;
    fb0.u = *(const uint4*)&Wt_s[(n0 + lr) * LDSTR + kc];
    fb1.u = *(const uint4*)&Wt_s[(n0 + 16 + lr) * LDSTR + kc];
#pragma unroll
    for (int mt = 0; mt < 4; ++mt) {
      FragU fa;
      fa.u = *(const uint4*)&As_s[(mt * 16 + lr) * LDSTR + kc];
      acc[mt][0] = __builtin_amdgcn_mfma_f32_16x16x32_bf16(fa.b, fb0.b, acc[mt][0], 0, 0, 0);
      acc[mt][1] = __builtin_amdgcn_mfma_f32_16x16x32_bf16(fa.b, fb1.b, acc[mt][1], 0, 0, 0);
    }
  }
  __syncthreads();   // all LDS reads complete before region reuse

  // t -> LDS (stride 129: conflict-free column reads); stage Wl
#pragma unroll
  for (int mt = 0; mt < 4; ++mt) {
#pragma unroll
    for (int nt = 0; nt < 2; ++nt) {
      int col = n0 + nt * 16 + lr;
      float bv = b2[col];
#pragma unroll
      for (int r = 0; r < 4; ++r)
        ts[(mt * 16 + quad * 4 + r) * 129 + col] = acc[mt][nt][r] + bv;
    }
  }
  for (int i = tid; i < 192 * 16; i += 256) Wls[i] = Wl[i];
  __syncthreads();

  // z = [t, s] @ Wl + bl; 4 lanes per row, 48 k-dims each, shfl reduce
  int q = lane & 3;
  int mrow = w * 16 + (lane >> 2);
  int b = rbase + mrow;
  float z[16];
#pragma unroll
  for (int c = 0; c < 16; ++c) z[c] = 0.f;
  int k0 = q * 48;
  for (int kk = 0; kk < 48; ++kk) {
    int k = k0 + kk;
    float xv = (k < 128) ? ts[mrow * 129 + k] : s_in[(long)b * 64 + (k - 128)];
    const float* wp = Wls + k * 16;
#pragma unroll
    for (int c = 0; c < 16; ++c) z[c] = fmaf(xv, wp[c], z[c]);
  }
#pragma unroll
  for (int c = 0; c < 16; ++c) {
    z[c] += __shfl_xor(z[c], 1);
    z[c] += __shfl_xor(z[c], 2);
  }
  if (q == 0) {
#pragma unroll
    for (int c = 0; c < 16; ++c) z[c] += bl[c];
    float mx = z[0];
#pragma unroll
    for (int c = 1; c < 16; ++c) mx = fmaxf(mx, z[c]);
    float sum = 0.f;
#pragma unroll
    for (int c = 0; c < 16; ++c) sum += expf(z[c] - mx);
    float lse = mx + logf(sum);
    float4* ob = (float4*)(out + (long)b * 16);
    ob[0] = make_float4(z[0] - lse, z[1] - lse, z[2] - lse, z[3] - lse);
    ob[1] = make_float4(z[4] - lse, z[5] - lse, z[6] - lse, z[7] - lse);
    ob[2] = make_float4(z[8] - lse, z[9] - lse, z[10] - lse, z[11] - lse);
    ob[3] = make_float4(z[12] - lse, z[13] - lse, z[14] - lse, z[15] - lse);
  }
}

// ---- full-row CSR spmm, f16 packed math (R0 geometry + proven micro-opts) ----
// 4 waves/block, 1 row/wave, 4 edge-groups x 16 lanes x 8 feats, 2x unroll.
// Edge word broadcast within each 16-lane group; 16B f16 feature loads; packed FMA.

__global__ __launch_bounds__(256) void spmm_row_kernel(const int* __restrict__ offs,
                                                       const uint* __restrict__ edat4,
                                                       const unsigned short* __restrict__ a,
                                                       const float* __restrict__ bias,
                                                       unsigned short* __restrict__ h1,
                                                       const uint* __restrict__ keep) {
  int wave = threadIdx.x >> 6;
  int lane = threadIdx.x & 63;
  int r = blockIdx.x * 4 + wave;           // grid = 25000, exact
  if (!keep_test(keep, r)) return;
  int g = lane >> 4, l = lane & 15;
  int s = offs[r], e = offs[r + 1];
  __half2 acc[4] = {h2zero(), h2zero(), h2zero(), h2zero()};
  int j = s + g;
  for (; j + 4 < e; j += 8) {
    uint e0 = edat4[j];
    uint e1 = edat4[j + 4];
    uint4 u0 = *(const uint4*)(a + (size_t)(e0 & 0x1FFFFu) * 128 + l * 8);
    uint4 u1 = *(const uint4*)(a + (size_t)(e1 & 0x1FFFFu) * 128 + l * 8);
    fma_row_h(acc, edge_vh2(e0), u0);
    fma_row_h(acc, edge_vh2(e1), u1);
  }
  if (j < e) {
    uint e0 = edat4[j];
    uint4 u = *(const uint4*)(a + (size_t)(e0 & 0x1FFFFu) * 128 + l * 8);
    fma_row_h(acc, edge_vh2(e0), u);
  }
#pragma unroll
  for (int k = 0; k < 4; ++k) {
    acc[k] = h2shfl_add(acc[k], 16);
    acc[k] = h2shfl_add(acc[k], 32);
  }
  if (g == 0) {
    const float* bp = bias + l * 8;
    float4 b0 = *(const float4*)bp;
    float4 b1v = *(const float4*)(bp + 4);
    uint4 o;
    o.x = relu2(__builtin_bit_cast(uint, __hadd2(acc[0], __floats2half2_rn(b0.x, b0.y))));
    o.y = relu2(__builtin_bit_cast(uint, __hadd2(acc[1], __floats2half2_rn(b0.z, b0.w))));
    o.z = relu2(__builtin_bit_cast(uint, __hadd2(acc[2], __floats2half2_rn(b1v.x, b1v.y))));
    o.w = relu2(__builtin_bit_cast(uint, __hadd2(acc[3], __floats2half2_rn(b1v.z, b1v.w))));
    *(uint4*)(h1 + (size_t)r * 128 + l * 8) = o;
  }
}

__global__ __launch_bounds__(256) void spmm_sel_kernel(const int* __restrict__ offs,
                                                       const uint* __restrict__ edat4,
                                                       const unsigned short* __restrict__ h1,
                                                       const int* __restrict__ index,
                                                       float* __restrict__ g2) {
  int wave = threadIdx.x >> 6;
  int lane = threadIdx.x & 63;
  int b = blockIdx.x * 4 + wave;           // grid = 2048, exact
  int g = lane >> 4, l = lane & 15;
  int r = index[b];
  int s = offs[r], e = offs[r + 1];
  __half2 acc[4] = {h2zero(), h2zero(), h2zero(), h2zero()};
  int j = s + g;
  for (; j + 4 < e; j += 8) {
    uint e0 = edat4[j];
    uint e1 = edat4[j + 4];
    uint4 u0 = *(const uint4*)(h1 + (size_t)(e0 & 0x1FFFFu) * 128 + l * 8);
    uint4 u1 = *(const uint4*)(h1 + (size_t)(e1 & 0x1FFFFu) * 128 + l * 8);
    fma_row_h(acc, edge_vh2(e0), u0);
    fma_row_h(acc, edge_vh2(e1), u1);
  }
  if (j < e) {
    uint e0 = edat4[j];
    uint4 u = *(const uint4*)(h1 + (size_t)(e0 & 0x1FFFFu) * 128 + l * 8);
    fma_row_h(acc, edge_vh2(e0), u);
  }
#pragma unroll
  for (int k = 0; k < 4; ++k) {
    acc[k] = h2shfl_add(acc[k], 16);
    acc[k] = h2shfl_add(acc[k], 32);
  }
  if (g == 0) {
    float* op = g2 + (size_t)b * 128 + l * 8;
    *(float4*)op = make_float4(__low2float(acc[0]), __high2float(acc[0]),
                               __low2float(acc[1]), __high2float(acc[1]));
    *(float4*)(op + 4) = make_float4(__low2float(acc[2]), __high2float(acc[2]),
                                     __low2float(acc[3]), __high2float(acc[3]));
  }
}

// ---------------- launch ----------------

extern "C" void kernel_launch(void* const* d_in, const int* in_sizes, int n_in,
                              void* d_out, int out_size, void* d_ws, size_t ws_size,
                              hipStream_t stream) {
  const float* s_in  = (const float*)d_in[0];
  const float* x     = (const float*)d_in[1];
  const int*   row   = (const int*)d_in[2];
  const int*   col   = (const int*)d_in[3];
  const float* val   = (const float*)d_in[4];
  const int*   index = (const int*)d_in[5];
  const float* W1    = (const float*)d_in[6];
  const float* b1    = (const float*)d_in[7];
  const float* W2    = (const float*)d_in[8];
  const float* b2    = (const float*)d_in[9];
  const float* Wl    = (const float*)d_in[10];
  const float* bl    = (const float*)d_in[11];
  float* out = (float*)d_out;

  // workspace carve (~82 MB), 8B-aligned first
  ull* edat8 = (ull*)d_ws;                                           // [1.6M] binB out (8B edges)
  ull* ebuf1 = edat8 + N_EDGES;                                      // [1.6M] binA out / binC fallback
  uint* edat4 = (uint*)ebuf1;                                        // ALIAS: final 4B edges (binC out).
  // Safe: ebuf1 is dead after binB; binC fallback scratch at byte 8*beg never overlaps
  // edat4 writes (<= byte 4*(beg+n) <= 8*beg whenever n <= beg; fallback needs n > 2048,
  // p < 1e-100 at mean ~390 edges/sub-bucket).
  unsigned short* a  = (unsigned short*)(ebuf1 + N_EDGES);           // xW1 f16 [100000][128]
  unsigned short* h1 = a + (size_t)N_NODES * 128;                    // layer1 f16 [100000][128]
  float* g2   = (float*)(h1 + (size_t)N_NODES * 128);                // sel spmm   [8192,128]
  int* sel    = (int*)(g2 + (size_t)BB * 128);                       // [100000] selected mask
  int* subcnt = sel + N_NODES;                                       // [3125]
  uint* keep  = (uint*)(subcnt + NSUB);                              // [3125] flag|sel bitmask
  int* offs   = (int*)(keep + NSUB);                                 // [100001] (binC writes)
  int* sub_offs = offs + (N_NODES + 1);                              // [3126]
  int* gcur1  = sub_offs + (NSUB + 1);                               // [49]
  int* gcur2  = gcur1 + NB1;                                         // [3125]

  hipMemsetAsync(sel, 0, (N_NODES + 2 * NSUB) * sizeof(int), stream);  // sel+subcnt+keep

  selbuild_kernel<<<BB / 256, 256, 0, stream>>>(index, sel, keep);
  selflag_kernel<<<4096, 256, 0, stream>>>(row, col, sel, keep);
  histsub_kernel<<<HWG, 256, 0, stream>>>(row, keep, subcnt);
  scanall_kernel<<<1, 1024, 0, stream>>>(subcnt, sub_offs, gcur1, gcur2);

  binA_kernel<<<512, 256, 0, stream>>>(row, col, val, keep, gcur1, ebuf1);
  binB_kernel<<<NB1 * 8, 256, 0, stream>>>(ebuf1, sub_offs, gcur2, edat8);
  binC_kernel<<<NSUB, 256, 0, stream>>>(sub_offs, edat8, ebuf1, edat4, offs);

  gemm1_kernel<<<(N_NODES + 127) / 128, 256, 0, stream>>>(x, W1, a, N_NODES);
  spmm_row_kernel<<<N_NODES / 4, 256, 0, stream>>>(offs, edat4, a, b1, h1, keep);
  spmm_sel_kernel<<<BB / 4, 256, 0, stream>>>(offs, edat4, h1, index, g2);
  gemm2f_kernel<<<BB / 64, 256, 0, stream>>>(g2, W2, b2, s_in, Wl, bl, out);
}